// Round 1
// baseline (83.702 us; speedup 1.0000x reference)
//
#include <hip/hip_runtime.h>
#include <cstdint>

#define N_NODES 4096
#define N_EDGES 131072
// out_size = N*(N-1)/2 = 8386560 floats; /4 = 2096640 quads; /256 = 8190 blocks exactly
#define OUT_ELEMS (N_NODES * (N_NODES - 1) / 2)
#define OUT_QUADS (OUT_ELEMS / 4)
// bitmap: one bit per output element. 8386560/32 = 262080 words; pad to 262144 (1 MiB)
#define BM_WORDS_PAD 262144

// Exact reference arithmetic: v(bs,bt) = Qt[0][1][bt] * Qt[t-1][bs][1] / Qt[t][bs][bt]
__device__ __forceinline__ void compute_vals(const float* __restrict__ Qt,
                                             const int* __restrict__ t_ptr,
                                             float* vals) {
    const int t = t_ptr[0];
    const float l0 = Qt[2], l1 = Qt[3];                              // Qt[0][1][bt]
    const float p0 = Qt[(t - 1) * 4 + 1], p1 = Qt[(t - 1) * 4 + 3]; // Qt[t-1][bs][1]
    const float e00 = Qt[t * 4 + 0], e01 = Qt[t * 4 + 1];
    const float e10 = Qt[t * 4 + 2], e11 = Qt[t * 4 + 3];
    vals[0] = l0 * p0 / e00;  // bs=0, bt=0
    vals[1] = l1 * p0 / e01;  // bs=0, bt=1
    vals[2] = l0 * p1 / e10;  // bs=1, bt=0
    vals[3] = l1 * p1 / e11;  // bs=1, bt=1
}

// triangle-linear index for i<j (row-major upper triangle, k=1)
__device__ __forceinline__ int tri_idx(int i, int j) {
    return i * (2 * N_NODES - i - 1) / 2 + (j - i - 1);
}

// Kernel 1: build both edge bitmaps with idempotent atomicOr.
// threads [0, N_EDGES)          -> x_t edges   -> bm[0 .. )
// threads [N_EDGES, 2*N_EDGES)  -> x_start     -> bm[BM_WORDS_PAD .. )
__global__ void gt_build_bitmaps(const int* __restrict__ et,
                                 const int* __restrict__ es,
                                 uint32_t* __restrict__ bm) {
    int e = blockIdx.x * blockDim.x + threadIdx.x;
    const int* __restrict__ lst;
    uint32_t* __restrict__ map;
    if (e < N_EDGES) {
        lst = et;
        map = bm;
    } else {
        lst = es;
        map = bm + BM_WORDS_PAD;
        e -= N_EDGES;
    }
    int i = lst[e];
    int j = lst[N_EDGES + e];
    if (i < j) {
        int k = tri_idx(i, j);
        atomicOr(&map[k >> 5], 1u << (k & 31));
    }
}

// Kernel 2: single coalesced sweep. Each thread emits one float4 (4 consecutive
// outputs); the 4 bits live in one 32-bit word of each bitmap (4 | 32).
__global__ void gt_write(const float* __restrict__ Qt,
                         const int* __restrict__ t_ptr,
                         const uint32_t* __restrict__ bm,
                         float4* __restrict__ out) {
    float vals[4];
    compute_vals(Qt, t_ptr, vals);

    int tid = blockIdx.x * blockDim.x + threadIdx.x;  // exactly OUT_QUADS threads
    int w = tid >> 3;                // bitmap word index (8 threads share a word)
    int sh = (tid & 7) * 4;          // bit offset of this thread's 4 outputs
    uint32_t wt = bm[w] >> sh;
    uint32_t ws = bm[BM_WORDS_PAD + w] >> sh;

    float r[4];
#pragma unroll
    for (int k = 0; k < 4; ++k) {
        bool bt = (wt >> k) & 1u;
        bool bs = (ws >> k) & 1u;
        r[k] = bs ? (bt ? vals[3] : vals[2]) : (bt ? vals[1] : vals[0]);
    }
    out[tid] = make_float4(r[0], r[1], r[2], r[3]);
}

extern "C" void kernel_launch(void* const* d_in, const int* in_sizes, int n_in,
                              void* d_out, int out_size, void* d_ws, size_t ws_size,
                              hipStream_t stream) {
    const float* Qt = (const float*)d_in[0];
    const int* et = (const int*)d_in[1];
    const int* es = (const int*)d_in[2];
    const int* t_ptr = (const int*)d_in[3];
    float* out = (float*)d_out;
    uint32_t* bm = (uint32_t*)d_ws;  // [2][BM_WORDS_PAD] words = 2 MiB

    // zero both bitmaps (workspace is re-poisoned by the harness each iteration)
    hipMemsetAsync(bm, 0, 2 * BM_WORDS_PAD * sizeof(uint32_t), stream);
    gt_build_bitmaps<<<(2 * N_EDGES) / 256, 256, 0, stream>>>(et, es, bm);
    gt_write<<<OUT_QUADS / 256, 256, 0, stream>>>(Qt, t_ptr, bm, (float4*)out);
}